// Round 1
// baseline (271.671 us; speedup 1.0000x reference)
//
#include <hip/hip_runtime.h>

#define N 12288
#define M (2 * N)          // keys (t_j) + queries (-s_i)
#define DIN 128
#define DOUT 64
#define NBIN 8192
#define BSHIFT 19          // 32 - log2(NBIN)
#define NCHUNK 384         // M / 64

// monotone float -> ordered u32 (order-preserving bit transform)
__device__ __forceinline__ unsigned f_ord(float x) {
    unsigned b = __float_as_uint(x);
    return (b & 0x80000000u) ? ~b : (b | 0x80000000u);
}
__device__ __forceinline__ float ord_f(unsigned u) {
    unsigned b = (u & 0x80000000u) ? (u & 0x7FFFFFFFu) : ~u;
    return __uint_as_float(b);
}
__device__ __forceinline__ int t_bin(float x) { return (int)(f_ord(x) >> BSHIFT); }

struct Args {
    const float *h, *W, *a;
    float *Wh, *s, *t, *tblkmax, *Thdr;
    unsigned long long *vals64;     // (ordered(val)<<32)|pi — unique total order
    float *tfin;
    int *idfin, *binstart;
    float2 *VU, *sc;                // per-chunk aggregates {v,u} published by k45
    int *cnt;                       // k45 arrival counter (zeroed by k1)
    float *out;
};

// ---------- K1: Wh = h@W, s, t, per-block max(t) (384 blocks x 128) ---------
__global__ __launch_bounds__(128) void k1_gemm(Args A) {
    __shared__ float4 sm4[3072];               // 48 KB: W 32K + h-tile 16K
    __shared__ float wmax[2];
    int tid = threadIdx.x, wave = tid >> 6, lane = tid & 63, blk = blockIdx.x;
    if (blk == 0 && tid == 0) *A.cnt = 0;      // reset k45 barrier counter
    float4* Ws4 = sm4;                         // W[k][c4]  (2048)
    float4* hs4 = sm4 + 2048;                  // h[r][k4]  (1024: 32 rows)
    const float4* W4 = (const float4*)A.W;
    #pragma unroll
    for (int e = tid; e < 2048; e += 128) Ws4[e] = W4[e];
    int row0 = blk * 32;
    const float4* h4 = (const float4*)(A.h + (size_t)row0 * DIN);
    #pragma unroll
    for (int e = tid; e < 1024; e += 128) hs4[e] = h4[e];
    __syncthreads();
    int c0 = lane & 15, rq = lane >> 4;
    int rbase = wave * 16 + rq * 4;            // 2 waves cover 32 rows
    float4 acc[4];
    #pragma unroll
    for (int rr = 0; rr < 4; ++rr) acc[rr] = make_float4(0.f, 0.f, 0.f, 0.f);
    #pragma unroll 2
    for (int kk = 0; kk < 32; ++kk) {
        float4 w0 = Ws4[(4 * kk + 0) * 16 + c0];
        float4 w1 = Ws4[(4 * kk + 1) * 16 + c0];
        float4 w2 = Ws4[(4 * kk + 2) * 16 + c0];
        float4 w3 = Ws4[(4 * kk + 3) * 16 + c0];
        #pragma unroll
        for (int rr = 0; rr < 4; ++rr) {
            float4 hv = hs4[(rbase + rr) * 32 + kk];
            acc[rr].x = fmaf(hv.x, w0.x, acc[rr].x);
            acc[rr].y = fmaf(hv.x, w0.y, acc[rr].y);
            acc[rr].z = fmaf(hv.x, w0.z, acc[rr].z);
            acc[rr].w = fmaf(hv.x, w0.w, acc[rr].w);
            acc[rr].x = fmaf(hv.y, w1.x, acc[rr].x);
            acc[rr].y = fmaf(hv.y, w1.y, acc[rr].y);
            acc[rr].z = fmaf(hv.y, w1.z, acc[rr].z);
            acc[rr].w = fmaf(hv.y, w1.w, acc[rr].w);
            acc[rr].x = fmaf(hv.z, w2.x, acc[rr].x);
            acc[rr].y = fmaf(hv.z, w2.y, acc[rr].y);
            acc[rr].z = fmaf(hv.z, w2.z, acc[rr].z);
            acc[rr].w = fmaf(hv.z, w2.w, acc[rr].w);
            acc[rr].x = fmaf(hv.w, w3.x, acc[rr].x);
            acc[rr].y = fmaf(hv.w, w3.y, acc[rr].y);
            acc[rr].z = fmaf(hv.w, w3.z, acc[rr].z);
            acc[rr].w = fmaf(hv.w, w3.w, acc[rr].w);
        }
    }
    float4 a1 = ((const float4*)A.a)[c0];
    float4 a2 = ((const float4*)A.a)[16 + c0];
    float tmax = -3.4e38f;
    #pragma unroll
    for (int rr = 0; rr < 4; ++rr) {
        int row = row0 + rbase + rr;
        ((float4*)A.Wh)[(size_t)row * 16 + c0] = acc[rr];
        float sv = acc[rr].x * a1.x + acc[rr].y * a1.y + acc[rr].z * a1.z + acc[rr].w * a1.w;
        float tv = acc[rr].x * a2.x + acc[rr].y * a2.y + acc[rr].z * a2.z + acc[rr].w * a2.w;
        #pragma unroll
        for (int off = 8; off; off >>= 1) {     // reduce over 16-lane group
            sv += __shfl_xor(sv, off, 64);
            tv += __shfl_xor(tv, off, 64);
        }
        if (c0 == 0) { A.s[row] = sv; A.t[row] = tv; }
        tmax = fmaxf(tmax, tv);
    }
    tmax = fmaxf(tmax, __shfl_xor(tmax, 16, 64));
    tmax = fmaxf(tmax, __shfl_xor(tmax, 32, 64));
    if (lane == 0) wmax[wave] = tmax;
    __syncthreads();
    if (tid == 0) A.tblkmax[blk] = fmaxf(wmax[0], wmax[1]);
}

// ---------- K2: LDS hist + pre-hist + scan + T + packed-key scatter ----------
__global__ __launch_bounds__(1024) void k2_sort(Args A) {
    __shared__ int hist[NBIN];                  // 32 KB
    __shared__ int pre[NBIN];                   // 32 KB
    __shared__ int wtot[16];
    __shared__ float fmax_[16];
    int tid = threadIdx.x, lane = tid & 63, wave = tid >> 6, blk = blockIdx.x;
    #pragma unroll
    for (int e = tid; e < NBIN; e += 1024) { hist[e] = 0; pre[e] = 0; }
    __syncthreads();
    #pragma unroll 4
    for (int e = tid; e < M; e += 1024) {
        float v = (e < N) ? A.t[e] : -A.s[e - N];
        atomicAdd(&hist[t_bin(v)], 1);
    }
    int my0 = blk * 1024;
    #pragma unroll 4
    for (int e = tid; e < my0; e += 1024) {
        float v = (e < N) ? A.t[e] : -A.s[e - N];
        atomicAdd(&pre[t_bin(v)], 1);
    }
    __syncthreads();
    int b0 = tid * 8;
    int c8[8]; int sum = 0;
    #pragma unroll
    for (int g = 0; g < 8; ++g) { c8[g] = sum; sum += hist[b0 + g]; }
    int inc = sum;
    #pragma unroll
    for (int off = 1; off < 64; off <<= 1) {
        int nb = __shfl_up(inc, off, 64);
        if (lane >= off) inc += nb;
    }
    if (lane == 63) wtot[wave] = inc;
    __syncthreads();
    int wbase = 0;
    #pragma unroll
    for (int w = 0; w < 16; ++w) wbase += (w < wave) ? wtot[w] : 0;
    int tstart = wbase + inc - sum;
    #pragma unroll
    for (int g = 0; g < 8; ++g) {
        int bs = tstart + c8[g];
        hist[b0 + g] = bs;
        pre[b0 + g] += bs;
        A.binstart[b0 + g] = bs;                // benign duplicate across blocks
    }
    if (tid == 0 && blk == 0) A.binstart[NBIN] = M;
    float m = (tid < 384) ? A.tblkmax[tid] : -3.4e38f;
    #pragma unroll
    for (int off = 32; off; off >>= 1) m = fmaxf(m, __shfl_xor(m, off, 64));
    if (lane == 0) fmax_[wave] = m;
    __syncthreads();
    if (tid == 0) {
        float mm = fmax_[0];
        #pragma unroll
        for (int w = 1; w < 16; ++w) mm = fmaxf(mm, fmax_[w]);
        A.Thdr[0] = mm;
    }
    __syncthreads();
    {   // exactly one item per thread (slice == blockDim)
        int e = my0 + tid;
        float v = (e < N) ? A.t[e] : -A.s[e - N];
        int pi = (e < N) ? (e + N) : (e - N);   // queries sort before equal keys
        int pos = atomicAdd(&pre[t_bin(v)], 1);
        A.vals64[pos] = ((unsigned long long)f_ord(v) << 32) | (unsigned)pi;
    }
}

// ---------- K3: exact in-bin rank, 4 THREADS per position ----------
__global__ __launch_bounds__(256) void k3_rank(Args A) {
    __shared__ int parts[256];
    int tid = threadIdx.x;
    int li = tid & 63, sub = tid >> 6;
    int p = blockIdx.x * 64 + li;
    unsigned long long kp = A.vals64[p];
    int b = (int)(kp >> (32 + BSHIFT));
    int lo = A.binstart[b], hi = A.binstart[b + 1];
    int len = hi - lo;
    int qlen = (len + 3) >> 2;
    int qlo = lo + sub * qlen;
    if (qlo > hi) qlo = hi;
    int qhi = qlo + qlen;
    if (qhi > hi) qhi = hi;
    int cnt = 0;
    int q = qlo;
    while (q < qhi && (q & 3)) cnt += (int)(A.vals64[q++] < kp);
    int bend = q + ((qhi - q) & ~3);
    #pragma unroll 2
    for (; q < bend; q += 4) {
        ulonglong2 u0 = *(const ulonglong2*)&A.vals64[q];
        ulonglong2 u1 = *(const ulonglong2*)&A.vals64[q + 2];
        cnt += (int)(u0.x < kp) + (int)(u0.y < kp)
             + (int)(u1.x < kp) + (int)(u1.y < kp);
    }
    while (q < qhi) cnt += (int)(A.vals64[q++] < kp);
    parts[sub * 64 + li] = cnt;
    __syncthreads();
    if (sub == 0) {
        int tot = parts[li] + parts[64 + li] + parts[128 + li] + parts[192 + li];
        int pi = (int)(unsigned)(kp & 0xffffffffu);
        A.tfin[lo + tot] = ord_f((unsigned)(kp >> 32));
        A.idfin[lo + tot] = (pi >= N) ? (pi - N) : (pi + N);
    }
}

// ---------- K45: fused sums + global barrier + base/total sums + apply ------
// One wave per chunk (384 blocks x 64). Phase A computes the chunk's
// aggregates (old k4) and publishes them; a single arrival counter forms a
// grid barrier (all 384 one-wave blocks are trivially co-resident: 1.5
// waves/CU vs the 32 waves/CU limit, so the spin cannot deadlock). After the
// barrier each wave linearly sums the 384 published aggregates to get its
// exclusive forward base AND the grand totals (replacing k4b), then runs the
// old k5 apply loop reusing x[64] still live in registers — the duplicate
// gather pass of the old k5 is eliminated.
__global__ __launch_bounds__(64) void k45_fused(Args A) {
    int lane = threadIdx.x;
    int c = blockIdx.x;                         // 384 chunks
    float T = A.Thdr[0];
    float myval = A.tfin[c * 64 + lane];
    int myid = A.idfin[c * 64 + lane];
    float x[64];
    #pragma unroll
    for (int k = 0; k < 64; ++k) {              // 64 independent gathers
        int uid = __shfl(myid, k, 64);
        x[k] = (uid < N) ? A.Wh[(size_t)uid * DOUT + lane] : 0.f;
    }
    float av = 0.f, au = 0.f, svs = 0.f, sus = 0.f;
    #pragma unroll
    for (int k = 0; k < 64; ++k) {
        int uid = __shfl(myid, k, 64);
        if (uid < N) {
            float uval = __shfl(myval, k, 64);
            float wv = expf(0.2f * (uval - T));
            float w2 = wv * wv, w4 = w2 * w2;
            float wu = w4 * wv;                 // exp(uval-T) = wv^5
            av = fmaf(wv, x[k], av); au = fmaf(wu, x[k], au);
            svs += wv; sus += wu;
        }
    }
    // publish aggregates (plain stores), then release via the counter
    A.VU[c * 64 + lane] = make_float2(av, au);
    if (lane == 0) A.sc[c] = make_float2(svs, sus);
    __threadfence();                            // payload visible before arrive
    if (lane == 0) {
        __hip_atomic_fetch_add(A.cnt, 1, __ATOMIC_RELEASE, __HIP_MEMORY_SCOPE_AGENT);
        while (__hip_atomic_load(A.cnt, __ATOMIC_ACQUIRE, __HIP_MEMORY_SCOPE_AGENT) < NCHUNK)
            __builtin_amdgcn_s_sleep(2);        // whole wave parks here
    }
    __threadfence();                            // invalidate stale lines
    // forward-exclusive bases over chunks < c, and grand totals (U only)
    float bv = 0.f, bu = 0.f, bsv = 0.f, bsu = 0.f;
    #pragma unroll 4
    for (int j = 0; j < c; ++j) {
        float2 ag = A.VU[j * 64 + lane];
        bv += ag.x; bu += ag.y;
        if (lane == 0) { float2 q = A.sc[j]; bsv += q.x; bsu += q.y; }
    }
    float tu = bu, tus = bsu;
    #pragma unroll 4
    for (int j = c; j < NCHUNK; ++j) {
        float2 ag = A.VU[j * 64 + lane];
        tu += ag.y;
        if (lane == 0) { float2 q = A.sc[j]; tus += q.y; }
    }
    bsv = __shfl(bsv, 0, 64);
    bsu = __shfl(bsu, 0, 64);
    tus = __shfl(tus, 0, 64);
    // apply sweep (old k5 body; x[] reused from phase A)
    float rv = bv, ru = bu, rvs = bsv, rus = bsu;
    #pragma unroll
    for (int k = 0; k < 64; ++k) {
        float uval = __shfl(myval, k, 64);
        int uid = __shfl(myid, k, 64);
        if (uid < N) {                          // key: advance running sums
            float wv = expf(0.2f * (uval - T));
            float w2 = wv * wv, w4 = w2 * w2;
            float wu = w4 * wv;                 // exp(uval-T)
            rv = fmaf(wv, x[k], rv); ru = fmaf(wu, x[k], ru);
            rvs += wv; rus += wu;
        } else {                                // query: emit output row
            int i = uid - N;
            float si = -uval;
            float xx = si + T;
            float mm = fmaxf(xx, 0.2f * xx);
            float cp_ = expf(xx - mm);
            float cn_ = expf(0.2f * xx - mm);
            float num = cn_ * rv + cp_ * (tu - ru);
            float den = cn_ * rvs + cp_ * (tus - rus);
            float r = num / den;
            A.out[(size_t)i * DOUT + lane] = r > 0.f ? r : expm1f(r);
        }
    }
}

extern "C" void kernel_launch(void* const* d_in, const int* in_sizes, int n_in,
                              void* d_out, int out_size, void* d_ws, size_t ws_size,
                              hipStream_t stream) {
    float* ws = (float*)d_ws;
    size_t o = 0;
    Args A;
    A.h = (const float*)d_in[0];
    A.W = (const float*)d_in[1];
    A.a = (const float*)d_in[2];
    A.out = (float*)d_out;
    A.Wh      = ws + o; o += (size_t)N * DOUT;
    A.s       = ws + o; o += N;
    A.t       = ws + o; o += N;
    A.tblkmax = ws + o; o += NCHUNK;            // 384 k1 blocks
    A.Thdr    = ws + o; o += 16;                // keeps o 16B-aligned
    A.vals64  = (unsigned long long*)(ws + o); o += 2 * (size_t)M;
    A.tfin    = ws + o; o += M;
    A.VU      = (float2*)(ws + o); o += 2 * (size_t)NCHUNK * DOUT;
    A.sc      = (float2*)(ws + o); o += 2 * NCHUNK;
    A.idfin    = (int*)(ws + o); o += M;
    A.binstart = (int*)(ws + o); o += NBIN + 16;
    A.cnt      = (int*)(ws + o); o += 16;
    // ~4 MB total; counter zeroed by k1 each launch

    k1_gemm <<<N / 32, 128, 0, stream>>>(A);
    k2_sort <<<24, 1024, 0, stream>>>(A);
    k3_rank <<<M / 64, 256, 0, stream>>>(A);
    k45_fused<<<NCHUNK, 64, 0, stream>>>(A);
}

// Round 3
// 202.699 us; speedup vs baseline: 1.3403x; 1.3403x over previous
//
#include <hip/hip_runtime.h>

#define N 12288
#define M (2 * N)          // keys (t_j) + queries (-s_i)
#define DIN 128
#define DOUT 64
#define NBIN 8192
#define BSHIFT 19          // 32 - log2(NBIN)
#define NCHUNK 384         // M / 64

// monotone float -> ordered u32 (order-preserving bit transform)
__device__ __forceinline__ unsigned f_ord(float x) {
    unsigned b = __float_as_uint(x);
    return (b & 0x80000000u) ? ~b : (b | 0x80000000u);
}
__device__ __forceinline__ float ord_f(unsigned u) {
    unsigned b = (u & 0x80000000u) ? (u & 0x7FFFFFFFu) : ~u;
    return __uint_as_float(b);
}
__device__ __forceinline__ int t_bin(float x) { return (int)(f_ord(x) >> BSHIFT); }

struct Args {
    const float *h, *W, *a;
    float *Wh, *s, *t, *tblkmax, *Thdr;
    unsigned long long *vals64;     // (ordered(val)<<32)|pi — unique total order
    float *tfin;
    int *idfin, *binstart;
    float2 *VU, *sc;                // per-chunk aggregates {v,u}
    int *cnt;                       // single arrival-counter barrier
    float *out;
};

// ---------- K1: Wh = h@W, s, t, per-block max(t) (384 blocks x 128) ---------
__global__ __launch_bounds__(128) void k1_gemm(Args A) {
    __shared__ float4 sm4[3072];               // 48 KB: W 32K + h-tile 16K
    __shared__ float wmax[2];
    int tid = threadIdx.x, wave = tid >> 6, lane = tid & 63, blk = blockIdx.x;
    if (blk == 0 && tid == 0) A.cnt[0] = 0;    // reset k45 barrier counter
    float4* Ws4 = sm4;                         // W[k][c4]  (2048)
    float4* hs4 = sm4 + 2048;                  // h[r][k4]  (1024: 32 rows)
    const float4* W4 = (const float4*)A.W;
    #pragma unroll
    for (int e = tid; e < 2048; e += 128) Ws4[e] = W4[e];
    int row0 = blk * 32;
    const float4* h4 = (const float4*)(A.h + (size_t)row0 * DIN);
    #pragma unroll
    for (int e = tid; e < 1024; e += 128) hs4[e] = h4[e];
    __syncthreads();
    int c0 = lane & 15, rq = lane >> 4;
    int rbase = wave * 16 + rq * 4;            // 2 waves cover 32 rows
    float4 acc[4];
    #pragma unroll
    for (int rr = 0; rr < 4; ++rr) acc[rr] = make_float4(0.f, 0.f, 0.f, 0.f);
    #pragma unroll 2
    for (int kk = 0; kk < 32; ++kk) {
        float4 w0 = Ws4[(4 * kk + 0) * 16 + c0];
        float4 w1 = Ws4[(4 * kk + 1) * 16 + c0];
        float4 w2 = Ws4[(4 * kk + 2) * 16 + c0];
        float4 w3 = Ws4[(4 * kk + 3) * 16 + c0];
        #pragma unroll
        for (int rr = 0; rr < 4; ++rr) {
            float4 hv = hs4[(rbase + rr) * 32 + kk];
            acc[rr].x = fmaf(hv.x, w0.x, acc[rr].x);
            acc[rr].y = fmaf(hv.x, w0.y, acc[rr].y);
            acc[rr].z = fmaf(hv.x, w0.z, acc[rr].z);
            acc[rr].w = fmaf(hv.x, w0.w, acc[rr].w);
            acc[rr].x = fmaf(hv.y, w1.x, acc[rr].x);
            acc[rr].y = fmaf(hv.y, w1.y, acc[rr].y);
            acc[rr].z = fmaf(hv.y, w1.z, acc[rr].z);
            acc[rr].w = fmaf(hv.y, w1.w, acc[rr].w);
            acc[rr].x = fmaf(hv.z, w2.x, acc[rr].x);
            acc[rr].y = fmaf(hv.z, w2.y, acc[rr].y);
            acc[rr].z = fmaf(hv.z, w2.z, acc[rr].z);
            acc[rr].w = fmaf(hv.z, w2.w, acc[rr].w);
            acc[rr].x = fmaf(hv.w, w3.x, acc[rr].x);
            acc[rr].y = fmaf(hv.w, w3.y, acc[rr].y);
            acc[rr].z = fmaf(hv.w, w3.z, acc[rr].z);
            acc[rr].w = fmaf(hv.w, w3.w, acc[rr].w);
        }
    }
    float4 a1 = ((const float4*)A.a)[c0];
    float4 a2 = ((const float4*)A.a)[16 + c0];
    float tmax = -3.4e38f;
    #pragma unroll
    for (int rr = 0; rr < 4; ++rr) {
        int row = row0 + rbase + rr;
        ((float4*)A.Wh)[(size_t)row * 16 + c0] = acc[rr];
        float sv = acc[rr].x * a1.x + acc[rr].y * a1.y + acc[rr].z * a1.z + acc[rr].w * a1.w;
        float tv = acc[rr].x * a2.x + acc[rr].y * a2.y + acc[rr].z * a2.z + acc[rr].w * a2.w;
        #pragma unroll
        for (int off = 8; off; off >>= 1) {     // reduce over 16-lane group
            sv += __shfl_xor(sv, off, 64);
            tv += __shfl_xor(tv, off, 64);
        }
        if (c0 == 0) { A.s[row] = sv; A.t[row] = tv; }
        tmax = fmaxf(tmax, tv);
    }
    tmax = fmaxf(tmax, __shfl_xor(tmax, 16, 64));
    tmax = fmaxf(tmax, __shfl_xor(tmax, 32, 64));
    if (lane == 0) wmax[wave] = tmax;
    __syncthreads();
    if (tid == 0) A.tblkmax[blk] = fmaxf(wmax[0], wmax[1]);
}

// ---------- K2: LDS hist + pre-hist + scan + T + packed-key scatter ----------
__global__ __launch_bounds__(1024) void k2_sort(Args A) {
    __shared__ int hist[NBIN];                  // 32 KB
    __shared__ int pre[NBIN];                   // 32 KB
    __shared__ int wtot[16];
    __shared__ float fmax_[16];
    int tid = threadIdx.x, lane = tid & 63, wave = tid >> 6, blk = blockIdx.x;
    #pragma unroll
    for (int e = tid; e < NBIN; e += 1024) { hist[e] = 0; pre[e] = 0; }
    __syncthreads();
    #pragma unroll 4
    for (int e = tid; e < M; e += 1024) {
        float v = (e < N) ? A.t[e] : -A.s[e - N];
        atomicAdd(&hist[t_bin(v)], 1);
    }
    int my0 = blk * 1024;
    #pragma unroll 4
    for (int e = tid; e < my0; e += 1024) {
        float v = (e < N) ? A.t[e] : -A.s[e - N];
        atomicAdd(&pre[t_bin(v)], 1);
    }
    __syncthreads();
    int b0 = tid * 8;
    int c8[8]; int sum = 0;
    #pragma unroll
    for (int g = 0; g < 8; ++g) { c8[g] = sum; sum += hist[b0 + g]; }
    int inc = sum;
    #pragma unroll
    for (int off = 1; off < 64; off <<= 1) {
        int nb = __shfl_up(inc, off, 64);
        if (lane >= off) inc += nb;
    }
    if (lane == 63) wtot[wave] = inc;
    __syncthreads();
    int wbase = 0;
    #pragma unroll
    for (int w = 0; w < 16; ++w) wbase += (w < wave) ? wtot[w] : 0;
    int tstart = wbase + inc - sum;
    #pragma unroll
    for (int g = 0; g < 8; ++g) {
        int bs = tstart + c8[g];
        hist[b0 + g] = bs;
        pre[b0 + g] += bs;
        A.binstart[b0 + g] = bs;                // benign duplicate across blocks
    }
    if (tid == 0 && blk == 0) A.binstart[NBIN] = M;
    float m = (tid < 384) ? A.tblkmax[tid] : -3.4e38f;
    #pragma unroll
    for (int off = 32; off; off >>= 1) m = fmaxf(m, __shfl_xor(m, off, 64));
    if (lane == 0) fmax_[wave] = m;
    __syncthreads();
    if (tid == 0) {
        float mm = fmax_[0];
        #pragma unroll
        for (int w = 1; w < 16; ++w) mm = fmaxf(mm, fmax_[w]);
        A.Thdr[0] = mm;
    }
    __syncthreads();
    {   // exactly one item per thread (slice == blockDim)
        int e = my0 + tid;
        float v = (e < N) ? A.t[e] : -A.s[e - N];
        int pi = (e < N) ? (e + N) : (e - N);   // queries sort before equal keys
        int pos = atomicAdd(&pre[t_bin(v)], 1);
        A.vals64[pos] = ((unsigned long long)f_ord(v) << 32) | (unsigned)pi;
    }
}

// ---------- K3: exact in-bin rank, 4 THREADS per position ----------
__global__ __launch_bounds__(256) void k3_rank(Args A) {
    __shared__ int parts[256];
    int tid = threadIdx.x;
    int li = tid & 63, sub = tid >> 6;
    int p = blockIdx.x * 64 + li;
    unsigned long long kp = A.vals64[p];
    int b = (int)(kp >> (32 + BSHIFT));
    int lo = A.binstart[b], hi = A.binstart[b + 1];
    int len = hi - lo;
    int qlen = (len + 3) >> 2;
    int qlo = lo + sub * qlen;
    if (qlo > hi) qlo = hi;
    int qhi = qlo + qlen;
    if (qhi > hi) qhi = hi;
    int cnt = 0;
    int q = qlo;
    while (q < qhi && (q & 3)) cnt += (int)(A.vals64[q++] < kp);
    int bend = q + ((qhi - q) & ~3);
    #pragma unroll 2
    for (; q < bend; q += 4) {
        ulonglong2 u0 = *(const ulonglong2*)&A.vals64[q];
        ulonglong2 u1 = *(const ulonglong2*)&A.vals64[q + 2];
        cnt += (int)(u0.x < kp) + (int)(u0.y < kp)
             + (int)(u1.x < kp) + (int)(u1.y < kp);
    }
    while (q < qhi) cnt += (int)(A.vals64[q++] < kp);
    parts[sub * 64 + li] = cnt;
    __syncthreads();
    if (sub == 0) {
        int tot = parts[li] + parts[64 + li] + parts[128 + li] + parts[192 + li];
        int pi = (int)(unsigned)(kp & 0xffffffffu);
        A.tfin[lo + tot] = ord_f((unsigned)(kp >> 32));
        A.idfin[lo + tot] = (pi >= N) ? (pi - N) : (pi + N);
    }
}

// ---------- K45: fused sums + ONE barrier + ILP base-reduction + apply ------
// One wave per chunk (384 blocks x 64; all co-resident: 1.5 waves/CU vs the
// 32 waves/CU limit, so the arrival-counter spin cannot deadlock — this exact
// single-barrier structure ran to completion and passed in round 1).
// Round 1's 179 µs came from the post-barrier base loop: 384 iterations each
// with a coalesced load PLUS a divergent if(lane==0) scalar load -> ~2
// dependent remote-latency loads per iteration. Fix (no second barrier):
//  - scalar prefix/totals: lane-split over chunks + xor-butterfly reduce
//  - column prefix/totals: 8-wide explicitly batched loads (8 independent
//    float2 loads issued before any use), predicated accumulate for j < c.
__global__ __launch_bounds__(64) void k45_fused(Args A) {
    int lane = threadIdx.x;
    int c = blockIdx.x;                         // 384 chunks
    float T = A.Thdr[0];
    float myval = A.tfin[c * 64 + lane];
    int myid = A.idfin[c * 64 + lane];
    float x[64];
    #pragma unroll
    for (int k = 0; k < 64; ++k) {              // 64 independent gathers
        int uid = __shfl(myid, k, 64);
        x[k] = (uid < N) ? A.Wh[(size_t)uid * DOUT + lane] : 0.f;
    }
    float av = 0.f, au = 0.f, svs = 0.f, sus = 0.f;
    #pragma unroll
    for (int k = 0; k < 64; ++k) {
        int uid = __shfl(myid, k, 64);
        if (uid < N) {
            float uval = __shfl(myval, k, 64);
            float wv = expf(0.2f * (uval - T));
            float w2 = wv * wv, w4 = w2 * w2;
            float wu = w4 * wv;                 // exp(uval-T) = wv^5
            av = fmaf(wv, x[k], av); au = fmaf(wu, x[k], au);
            svs += wv; sus += wu;
        }
    }
    // publish aggregates (plain stores), release via counter
    A.VU[c * 64 + lane] = make_float2(av, au);
    if (lane == 0) A.sc[c] = make_float2(svs, sus);
    __threadfence();
    if (lane == 0) {
        __hip_atomic_fetch_add(&A.cnt[0], 1, __ATOMIC_RELEASE, __HIP_MEMORY_SCOPE_AGENT);
        while (__hip_atomic_load(&A.cnt[0], __ATOMIC_ACQUIRE, __HIP_MEMORY_SCOPE_AGENT) < NCHUNK)
            __builtin_amdgcn_s_sleep(2);        // whole wave parks here
    }
    __threadfence();
    // ---- scalar prefix (j<c) and total: lane-split, branch-free-coalesced --
    float psv = 0.f, psu = 0.f, tsu = 0.f;
    #pragma unroll
    for (int b = 0; b < 6; ++b) {
        int j = b * 64 + lane;                  // covers exactly 0..383
        float2 q = A.sc[j];
        tsu += q.y;
        if (j < c) { psv += q.x; psu += q.y; }
    }
    #pragma unroll
    for (int off = 32; off; off >>= 1) {
        psv += __shfl_xor(psv, off, 64);
        psu += __shfl_xor(psu, off, 64);
        tsu += __shfl_xor(tsu, off, 64);
    }
    // ---- column prefix (j<c) and total: 8-wide batched for ILP ------------
    float bv = 0.f, bu = 0.f, tu = 0.f;
    for (int j0 = 0; j0 < NCHUNK; j0 += 8) {
        float2 aa[8];
        #pragma unroll
        for (int k = 0; k < 8; ++k) aa[k] = A.VU[(size_t)(j0 + k) * 64 + lane];
        #pragma unroll
        for (int k = 0; k < 8; ++k) {
            tu += aa[k].y;
            if (j0 + k < c) { bv += aa[k].x; bu += aa[k].y; }
        }
    }
    // ---- apply sweep (old k5 body; x[] reused from phase A) ---------------
    float rv = bv, ru = bu, rvs = psv, rus = psu;
    float tus = tsu;
    #pragma unroll
    for (int k = 0; k < 64; ++k) {
        float uval = __shfl(myval, k, 64);
        int uid = __shfl(myid, k, 64);
        if (uid < N) {                          // key: advance running sums
            float wv = expf(0.2f * (uval - T));
            float w2 = wv * wv, w4 = w2 * w2;
            float wu = w4 * wv;                 // exp(uval-T)
            rv = fmaf(wv, x[k], rv); ru = fmaf(wu, x[k], ru);
            rvs += wv; rus += wu;
        } else {                                // query: emit output row
            int i = uid - N;
            float si = -uval;
            float xx = si + T;
            float mm = fmaxf(xx, 0.2f * xx);
            float cp_ = expf(xx - mm);
            float cn_ = expf(0.2f * xx - mm);
            float num = cn_ * rv + cp_ * (tu - ru);
            float den = cn_ * rvs + cp_ * (tus - rus);
            float r = num / den;
            A.out[(size_t)i * DOUT + lane] = r > 0.f ? r : expm1f(r);
        }
    }
}

extern "C" void kernel_launch(void* const* d_in, const int* in_sizes, int n_in,
                              void* d_out, int out_size, void* d_ws, size_t ws_size,
                              hipStream_t stream) {
    float* ws = (float*)d_ws;
    size_t o = 0;
    Args A;
    A.h = (const float*)d_in[0];
    A.W = (const float*)d_in[1];
    A.a = (const float*)d_in[2];
    A.out = (float*)d_out;
    A.Wh      = ws + o; o += (size_t)N * DOUT;
    A.s       = ws + o; o += N;
    A.t       = ws + o; o += N;
    A.tblkmax = ws + o; o += NCHUNK;            // 384 k1 blocks
    A.Thdr    = ws + o; o += 16;                // keeps o 16B-aligned
    A.vals64  = (unsigned long long*)(ws + o); o += 2 * (size_t)M;
    A.tfin    = ws + o; o += M;
    A.VU      = (float2*)(ws + o); o += 2 * (size_t)NCHUNK * DOUT;
    A.sc      = (float2*)(ws + o); o += 2 * NCHUNK;
    A.idfin    = (int*)(ws + o); o += M;
    A.binstart = (int*)(ws + o); o += NBIN + 16;
    A.cnt      = (int*)(ws + o); o += 16;
    // ~4 MB total; counter zeroed by k1 each launch

    k1_gemm <<<N / 32, 128, 0, stream>>>(A);
    k2_sort <<<24, 1024, 0, stream>>>(A);
    k3_rank <<<M / 64, 256, 0, stream>>>(A);
    k45_fused<<<NCHUNK, 64, 0, stream>>>(A);
}

// Round 4
// 195.867 us; speedup vs baseline: 1.3870x; 1.0349x over previous
//
#include <hip/hip_runtime.h>

#define N 12288
#define M (2 * N)          // keys (t_j) + queries (-s_i)
#define DIN 128
#define DOUT 64
#define NBIN 8192
#define BSHIFT 19          // 32 - log2(NBIN)
#define NCHUNK 384         // M / 64

// monotone float -> ordered u32 (order-preserving bit transform)
__device__ __forceinline__ unsigned f_ord(float x) {
    unsigned b = __float_as_uint(x);
    return (b & 0x80000000u) ? ~b : (b | 0x80000000u);
}
__device__ __forceinline__ float ord_f(unsigned u) {
    unsigned b = (u & 0x80000000u) ? (u & 0x7FFFFFFFu) : ~u;
    return __uint_as_float(b);
}
__device__ __forceinline__ int t_bin(float x) { return (int)(f_ord(x) >> BSHIFT); }

struct Args {
    const float *h, *W, *a;
    float *Wh, *s, *t, *tblkmax, *Thdr;
    unsigned long long *vals64;     // (ordered(val)<<32)|pi — unique total order
    float *tfin;
    int *idfin, *binstart;
    float2 *VU, *sc;                // per-chunk aggregates {v,u}
    int *cnt;                       // barrier: 16 sub-counters (128B apart) +
                                    //          master at [512] + done at [544]
    float *out;
};

// ---------- K1: Wh = h@W, s, t, per-block max(t) (384 blocks x 128) ---------
__global__ __launch_bounds__(128) void k1_gemm(Args A) {
    __shared__ float4 sm4[3072];               // 48 KB: W 32K + h-tile 16K
    __shared__ float wmax[2];
    int tid = threadIdx.x, wave = tid >> 6, lane = tid & 63, blk = blockIdx.x;
    if (blk == 0) {                            // reset k45 barrier cells
        if (tid < 16) A.cnt[tid * 32] = 0;
        else if (tid == 16) A.cnt[512] = 0;
        else if (tid == 17) A.cnt[544] = 0;
    }
    float4* Ws4 = sm4;                         // W[k][c4]  (2048)
    float4* hs4 = sm4 + 2048;                  // h[r][k4]  (1024: 32 rows)
    const float4* W4 = (const float4*)A.W;
    #pragma unroll
    for (int e = tid; e < 2048; e += 128) Ws4[e] = W4[e];
    int row0 = blk * 32;
    const float4* h4 = (const float4*)(A.h + (size_t)row0 * DIN);
    #pragma unroll
    for (int e = tid; e < 1024; e += 128) hs4[e] = h4[e];
    __syncthreads();
    int c0 = lane & 15, rq = lane >> 4;
    int rbase = wave * 16 + rq * 4;            // 2 waves cover 32 rows
    float4 acc[4];
    #pragma unroll
    for (int rr = 0; rr < 4; ++rr) acc[rr] = make_float4(0.f, 0.f, 0.f, 0.f);
    #pragma unroll 2
    for (int kk = 0; kk < 32; ++kk) {
        float4 w0 = Ws4[(4 * kk + 0) * 16 + c0];
        float4 w1 = Ws4[(4 * kk + 1) * 16 + c0];
        float4 w2 = Ws4[(4 * kk + 2) * 16 + c0];
        float4 w3 = Ws4[(4 * kk + 3) * 16 + c0];
        #pragma unroll
        for (int rr = 0; rr < 4; ++rr) {
            float4 hv = hs4[(rbase + rr) * 32 + kk];
            acc[rr].x = fmaf(hv.x, w0.x, acc[rr].x);
            acc[rr].y = fmaf(hv.x, w0.y, acc[rr].y);
            acc[rr].z = fmaf(hv.x, w0.z, acc[rr].z);
            acc[rr].w = fmaf(hv.x, w0.w, acc[rr].w);
            acc[rr].x = fmaf(hv.y, w1.x, acc[rr].x);
            acc[rr].y = fmaf(hv.y, w1.y, acc[rr].y);
            acc[rr].z = fmaf(hv.y, w1.z, acc[rr].z);
            acc[rr].w = fmaf(hv.y, w1.w, acc[rr].w);
            acc[rr].x = fmaf(hv.z, w2.x, acc[rr].x);
            acc[rr].y = fmaf(hv.z, w2.y, acc[rr].y);
            acc[rr].z = fmaf(hv.z, w2.z, acc[rr].z);
            acc[rr].w = fmaf(hv.z, w2.w, acc[rr].w);
            acc[rr].x = fmaf(hv.w, w3.x, acc[rr].x);
            acc[rr].y = fmaf(hv.w, w3.y, acc[rr].y);
            acc[rr].z = fmaf(hv.w, w3.z, acc[rr].z);
            acc[rr].w = fmaf(hv.w, w3.w, acc[rr].w);
        }
    }
    float4 a1 = ((const float4*)A.a)[c0];
    float4 a2 = ((const float4*)A.a)[16 + c0];
    float tmax = -3.4e38f;
    #pragma unroll
    for (int rr = 0; rr < 4; ++rr) {
        int row = row0 + rbase + rr;
        ((float4*)A.Wh)[(size_t)row * 16 + c0] = acc[rr];
        float sv = acc[rr].x * a1.x + acc[rr].y * a1.y + acc[rr].z * a1.z + acc[rr].w * a1.w;
        float tv = acc[rr].x * a2.x + acc[rr].y * a2.y + acc[rr].z * a2.z + acc[rr].w * a2.w;
        #pragma unroll
        for (int off = 8; off; off >>= 1) {     // reduce over 16-lane group
            sv += __shfl_xor(sv, off, 64);
            tv += __shfl_xor(tv, off, 64);
        }
        if (c0 == 0) { A.s[row] = sv; A.t[row] = tv; }
        tmax = fmaxf(tmax, tv);
    }
    tmax = fmaxf(tmax, __shfl_xor(tmax, 16, 64));
    tmax = fmaxf(tmax, __shfl_xor(tmax, 32, 64));
    if (lane == 0) wmax[wave] = tmax;
    __syncthreads();
    if (tid == 0) A.tblkmax[blk] = fmaxf(wmax[0], wmax[1]);
}

// ---------- K2: LDS hist + pre-hist + scan + T + packed-key scatter ----------
__global__ __launch_bounds__(1024) void k2_sort(Args A) {
    __shared__ int hist[NBIN];                  // 32 KB
    __shared__ int pre[NBIN];                   // 32 KB
    __shared__ int wtot[16];
    __shared__ float fmax_[16];
    int tid = threadIdx.x, lane = tid & 63, wave = tid >> 6, blk = blockIdx.x;
    #pragma unroll
    for (int e = tid; e < NBIN; e += 1024) { hist[e] = 0; pre[e] = 0; }
    __syncthreads();
    #pragma unroll 4
    for (int e = tid; e < M; e += 1024) {
        float v = (e < N) ? A.t[e] : -A.s[e - N];
        atomicAdd(&hist[t_bin(v)], 1);
    }
    int my0 = blk * 1024;
    #pragma unroll 4
    for (int e = tid; e < my0; e += 1024) {
        float v = (e < N) ? A.t[e] : -A.s[e - N];
        atomicAdd(&pre[t_bin(v)], 1);
    }
    __syncthreads();
    int b0 = tid * 8;
    int c8[8]; int sum = 0;
    #pragma unroll
    for (int g = 0; g < 8; ++g) { c8[g] = sum; sum += hist[b0 + g]; }
    int inc = sum;
    #pragma unroll
    for (int off = 1; off < 64; off <<= 1) {
        int nb = __shfl_up(inc, off, 64);
        if (lane >= off) inc += nb;
    }
    if (lane == 63) wtot[wave] = inc;
    __syncthreads();
    int wbase = 0;
    #pragma unroll
    for (int w = 0; w < 16; ++w) wbase += (w < wave) ? wtot[w] : 0;
    int tstart = wbase + inc - sum;
    #pragma unroll
    for (int g = 0; g < 8; ++g) {
        int bs = tstart + c8[g];
        hist[b0 + g] = bs;
        pre[b0 + g] += bs;
        A.binstart[b0 + g] = bs;                // benign duplicate across blocks
    }
    if (tid == 0 && blk == 0) A.binstart[NBIN] = M;
    float m = (tid < 384) ? A.tblkmax[tid] : -3.4e38f;
    #pragma unroll
    for (int off = 32; off; off >>= 1) m = fmaxf(m, __shfl_xor(m, off, 64));
    if (lane == 0) fmax_[wave] = m;
    __syncthreads();
    if (tid == 0) {
        float mm = fmax_[0];
        #pragma unroll
        for (int w = 1; w < 16; ++w) mm = fmaxf(mm, fmax_[w]);
        A.Thdr[0] = mm;
    }
    __syncthreads();
    {   // exactly one item per thread (slice == blockDim)
        int e = my0 + tid;
        float v = (e < N) ? A.t[e] : -A.s[e - N];
        int pi = (e < N) ? (e + N) : (e - N);   // queries sort before equal keys
        int pos = atomicAdd(&pre[t_bin(v)], 1);
        A.vals64[pos] = ((unsigned long long)f_ord(v) << 32) | (unsigned)pi;
    }
}

// ---------- K3: exact in-bin rank, 4 THREADS per position ----------
__global__ __launch_bounds__(256) void k3_rank(Args A) {
    __shared__ int parts[256];
    int tid = threadIdx.x;
    int li = tid & 63, sub = tid >> 6;
    int p = blockIdx.x * 64 + li;
    unsigned long long kp = A.vals64[p];
    int b = (int)(kp >> (32 + BSHIFT));
    int lo = A.binstart[b], hi = A.binstart[b + 1];
    int len = hi - lo;
    int qlen = (len + 3) >> 2;
    int qlo = lo + sub * qlen;
    if (qlo > hi) qlo = hi;
    int qhi = qlo + qlen;
    if (qhi > hi) qhi = hi;
    int cnt = 0;
    int q = qlo;
    while (q < qhi && (q & 3)) cnt += (int)(A.vals64[q++] < kp);
    int bend = q + ((qhi - q) & ~3);
    #pragma unroll 2
    for (; q < bend; q += 4) {
        ulonglong2 u0 = *(const ulonglong2*)&A.vals64[q];
        ulonglong2 u1 = *(const ulonglong2*)&A.vals64[q + 2];
        cnt += (int)(u0.x < kp) + (int)(u0.y < kp)
             + (int)(u1.x < kp) + (int)(u1.y < kp);
    }
    while (q < qhi) cnt += (int)(A.vals64[q++] < kp);
    parts[sub * 64 + li] = cnt;
    __syncthreads();
    if (sub == 0) {
        int tot = parts[li] + parts[64 + li] + parts[128 + li] + parts[192 + li];
        int pi = (int)(unsigned)(kp & 0xffffffffu);
        A.tfin[lo + tot] = ord_f((unsigned)(kp >> 32));
        A.idfin[lo + tot] = (pi >= N) ? (pi - N) : (pi + N);
    }
}

// ---------- K45: fused sums + low-contention barrier + ILP scans + apply ----
// One wave per chunk (384 blocks x 64; all co-resident: 1.5 waves/CU vs the
// 32 waves/CU limit, so the spin cannot deadlock).
// Round-3 evidence: k45 = 127 µs at VALUBusy 2.9% — the residual ~65 µs is
// the barrier: 384 device-scope RMWs on ONE line, polled by 384 waves
// (~400 cy each serialized ≈ 64 µs). Fix: two-level arrival (16 sub-counter
// lines, 24 RMWs each in parallel -> master -> done flag) and polling only a
// read-only 'done' line with s_sleep backoff. VU scan widened to 16-wide
// batches (24 batches of independent loads).
__global__ __launch_bounds__(64) void k45_fused(Args A) {
    int lane = threadIdx.x;
    int c = blockIdx.x;                         // 384 chunks
    float T = A.Thdr[0];
    float myval = A.tfin[c * 64 + lane];
    int myid = A.idfin[c * 64 + lane];
    float x[64];
    #pragma unroll
    for (int k = 0; k < 64; ++k) {              // 64 independent gathers
        int uid = __shfl(myid, k, 64);
        x[k] = (uid < N) ? A.Wh[(size_t)uid * DOUT + lane] : 0.f;
    }
    float av = 0.f, au = 0.f, svs = 0.f, sus = 0.f;
    #pragma unroll
    for (int k = 0; k < 64; ++k) {
        int uid = __shfl(myid, k, 64);
        if (uid < N) {
            float uval = __shfl(myval, k, 64);
            float wv = expf(0.2f * (uval - T));
            float w2 = wv * wv, w4 = w2 * w2;
            float wu = w4 * wv;                 // exp(uval-T) = wv^5
            av = fmaf(wv, x[k], av); au = fmaf(wu, x[k], au);
            svs += wv; sus += wu;
        }
    }
    // publish aggregates (plain stores), then two-level arrival
    A.VU[c * 64 + lane] = make_float2(av, au);
    if (lane == 0) A.sc[c] = make_float2(svs, sus);
    __threadfence();
    if (lane == 0) {
        int sub = c & 15;                       // 24 blocks per sub-counter
        int old = __hip_atomic_fetch_add(&A.cnt[sub * 32], 1,
                                         __ATOMIC_ACQ_REL, __HIP_MEMORY_SCOPE_AGENT);
        if (old == 23) {                        // last on this line
            int m = __hip_atomic_fetch_add(&A.cnt[512], 1,
                                           __ATOMIC_ACQ_REL, __HIP_MEMORY_SCOPE_AGENT);
            if (m == 15)                        // last master -> open the gate
                __hip_atomic_store(&A.cnt[544], 1,
                                   __ATOMIC_RELEASE, __HIP_MEMORY_SCOPE_AGENT);
        }
        while (!__hip_atomic_load(&A.cnt[544], __ATOMIC_ACQUIRE, __HIP_MEMORY_SCOPE_AGENT))
            __builtin_amdgcn_s_sleep(8);        // whole wave parks here
    }
    __threadfence();
    // ---- scalar prefix (j<c) and total: lane-split, coalesced -------------
    float psv = 0.f, psu = 0.f, tsu = 0.f;
    #pragma unroll
    for (int b = 0; b < 6; ++b) {
        int j = b * 64 + lane;                  // covers exactly 0..383
        float2 q = A.sc[j];
        tsu += q.y;
        if (j < c) { psv += q.x; psu += q.y; }
    }
    #pragma unroll
    for (int off = 32; off; off >>= 1) {
        psv += __shfl_xor(psv, off, 64);
        psu += __shfl_xor(psu, off, 64);
        tsu += __shfl_xor(tsu, off, 64);
    }
    // ---- column prefix (j<c) and total: 16-wide batched for ILP -----------
    float bv = 0.f, bu = 0.f, tu = 0.f;
    for (int j0 = 0; j0 < NCHUNK; j0 += 16) {
        float2 aa[16];
        #pragma unroll
        for (int k = 0; k < 16; ++k) aa[k] = A.VU[(size_t)(j0 + k) * 64 + lane];
        #pragma unroll
        for (int k = 0; k < 16; ++k) {
            tu += aa[k].y;
            if (j0 + k < c) { bv += aa[k].x; bu += aa[k].y; }
        }
    }
    // ---- apply sweep (old k5 body; x[] reused from phase A) ---------------
    float rv = bv, ru = bu, rvs = psv, rus = psu;
    float tus = tsu;
    #pragma unroll
    for (int k = 0; k < 64; ++k) {
        float uval = __shfl(myval, k, 64);
        int uid = __shfl(myid, k, 64);
        if (uid < N) {                          // key: advance running sums
            float wv = expf(0.2f * (uval - T));
            float w2 = wv * wv, w4 = w2 * w2;
            float wu = w4 * wv;                 // exp(uval-T)
            rv = fmaf(wv, x[k], rv); ru = fmaf(wu, x[k], ru);
            rvs += wv; rus += wu;
        } else {                                // query: emit output row
            int i = uid - N;
            float si = -uval;
            float xx = si + T;
            float mm = fmaxf(xx, 0.2f * xx);
            float cp_ = expf(xx - mm);
            float cn_ = expf(0.2f * xx - mm);
            float num = cn_ * rv + cp_ * (tu - ru);
            float den = cn_ * rvs + cp_ * (tus - rus);
            float r = num / den;
            A.out[(size_t)i * DOUT + lane] = r > 0.f ? r : expm1f(r);
        }
    }
}

extern "C" void kernel_launch(void* const* d_in, const int* in_sizes, int n_in,
                              void* d_out, int out_size, void* d_ws, size_t ws_size,
                              hipStream_t stream) {
    float* ws = (float*)d_ws;
    size_t o = 0;
    Args A;
    A.h = (const float*)d_in[0];
    A.W = (const float*)d_in[1];
    A.a = (const float*)d_in[2];
    A.out = (float*)d_out;
    A.Wh      = ws + o; o += (size_t)N * DOUT;
    A.s       = ws + o; o += N;
    A.t       = ws + o; o += N;
    A.tblkmax = ws + o; o += NCHUNK;            // 384 k1 blocks
    A.Thdr    = ws + o; o += 16;                // keeps o 16B-aligned
    A.vals64  = (unsigned long long*)(ws + o); o += 2 * (size_t)M;
    A.tfin    = ws + o; o += M;
    A.VU      = (float2*)(ws + o); o += 2 * (size_t)NCHUNK * DOUT;
    A.sc      = (float2*)(ws + o); o += 2 * NCHUNK;
    A.idfin    = (int*)(ws + o); o += M;
    A.binstart = (int*)(ws + o); o += NBIN + 16;
    A.cnt      = (int*)(ws + o); o += 1024;     // 16 sub-lines + master + done
    // ~4 MB total; barrier cells zeroed by k1 each launch

    k1_gemm <<<N / 32, 128, 0, stream>>>(A);
    k2_sort <<<24, 1024, 0, stream>>>(A);
    k3_rank <<<M / 64, 256, 0, stream>>>(A);
    k45_fused<<<NCHUNK, 64, 0, stream>>>(A);
}

// Round 5
// 159.032 us; speedup vs baseline: 1.7083x; 1.2316x over previous
//
#include <hip/hip_runtime.h>

#define N 12288
#define M (2 * N)          // keys (t_j) + queries (-s_i)
#define DIN 128
#define DOUT 64
#define NBIN 8192
#define BSHIFT 19          // 32 - log2(NBIN)
#define NCHUNK 384         // M / 64

// monotone float -> ordered u32 (order-preserving bit transform)
__device__ __forceinline__ unsigned f_ord(float x) {
    unsigned b = __float_as_uint(x);
    return (b & 0x80000000u) ? ~b : (b | 0x80000000u);
}
__device__ __forceinline__ float ord_f(unsigned u) {
    unsigned b = (u & 0x80000000u) ? (u & 0x7FFFFFFFu) : ~u;
    return __uint_as_float(b);
}
__device__ __forceinline__ int t_bin(float x) { return (int)(f_ord(x) >> BSHIFT); }

struct Args {
    const float *h, *W, *a;
    float *Wh, *s, *t, *tblkmax, *Thdr;
    unsigned long long *vals64;     // (ordered(val)<<32)|pi — unique total order
    float *tfin;
    int *idfin, *binstart;
    float2 *VU, *sc;                // per-chunk aggregates {v,u}
    int *cnt;                       // cnt[0]=arrival counter, cnt[32]=done flag
    float *out;
};

// ---------- K1: Wh = h@W, s, t, per-block max(t) (384 blocks x 128) ---------
__global__ __launch_bounds__(128) void k1_gemm(Args A) {
    __shared__ float4 sm4[3072];               // 48 KB: W 32K + h-tile 16K
    __shared__ float wmax[2];
    int tid = threadIdx.x, wave = tid >> 6, lane = tid & 63, blk = blockIdx.x;
    if (blk == 0) {                            // reset k45 barrier cells
        if (tid == 0) A.cnt[0] = 0;
        else if (tid == 1) A.cnt[32] = 0;
    }
    float4* Ws4 = sm4;                         // W[k][c4]  (2048)
    float4* hs4 = sm4 + 2048;                  // h[r][k4]  (1024: 32 rows)
    const float4* W4 = (const float4*)A.W;
    #pragma unroll
    for (int e = tid; e < 2048; e += 128) Ws4[e] = W4[e];
    int row0 = blk * 32;
    const float4* h4 = (const float4*)(A.h + (size_t)row0 * DIN);
    #pragma unroll
    for (int e = tid; e < 1024; e += 128) hs4[e] = h4[e];
    __syncthreads();
    int c0 = lane & 15, rq = lane >> 4;
    int rbase = wave * 16 + rq * 4;            // 2 waves cover 32 rows
    float4 acc[4];
    #pragma unroll
    for (int rr = 0; rr < 4; ++rr) acc[rr] = make_float4(0.f, 0.f, 0.f, 0.f);
    #pragma unroll 2
    for (int kk = 0; kk < 32; ++kk) {
        float4 w0 = Ws4[(4 * kk + 0) * 16 + c0];
        float4 w1 = Ws4[(4 * kk + 1) * 16 + c0];
        float4 w2 = Ws4[(4 * kk + 2) * 16 + c0];
        float4 w3 = Ws4[(4 * kk + 3) * 16 + c0];
        #pragma unroll
        for (int rr = 0; rr < 4; ++rr) {
            float4 hv = hs4[(rbase + rr) * 32 + kk];
            acc[rr].x = fmaf(hv.x, w0.x, acc[rr].x);
            acc[rr].y = fmaf(hv.x, w0.y, acc[rr].y);
            acc[rr].z = fmaf(hv.x, w0.z, acc[rr].z);
            acc[rr].w = fmaf(hv.x, w0.w, acc[rr].w);
            acc[rr].x = fmaf(hv.y, w1.x, acc[rr].x);
            acc[rr].y = fmaf(hv.y, w1.y, acc[rr].y);
            acc[rr].z = fmaf(hv.y, w1.z, acc[rr].z);
            acc[rr].w = fmaf(hv.y, w1.w, acc[rr].w);
            acc[rr].x = fmaf(hv.z, w2.x, acc[rr].x);
            acc[rr].y = fmaf(hv.z, w2.y, acc[rr].y);
            acc[rr].z = fmaf(hv.z, w2.z, acc[rr].z);
            acc[rr].w = fmaf(hv.z, w2.w, acc[rr].w);
            acc[rr].x = fmaf(hv.w, w3.x, acc[rr].x);
            acc[rr].y = fmaf(hv.w, w3.y, acc[rr].y);
            acc[rr].z = fmaf(hv.w, w3.z, acc[rr].z);
            acc[rr].w = fmaf(hv.w, w3.w, acc[rr].w);
        }
    }
    float4 a1 = ((const float4*)A.a)[c0];
    float4 a2 = ((const float4*)A.a)[16 + c0];
    float tmax = -3.4e38f;
    #pragma unroll
    for (int rr = 0; rr < 4; ++rr) {
        int row = row0 + rbase + rr;
        ((float4*)A.Wh)[(size_t)row * 16 + c0] = acc[rr];
        float sv = acc[rr].x * a1.x + acc[rr].y * a1.y + acc[rr].z * a1.z + acc[rr].w * a1.w;
        float tv = acc[rr].x * a2.x + acc[rr].y * a2.y + acc[rr].z * a2.z + acc[rr].w * a2.w;
        #pragma unroll
        for (int off = 8; off; off >>= 1) {     // reduce over 16-lane group
            sv += __shfl_xor(sv, off, 64);
            tv += __shfl_xor(tv, off, 64);
        }
        if (c0 == 0) { A.s[row] = sv; A.t[row] = tv; }
        tmax = fmaxf(tmax, tv);
    }
    tmax = fmaxf(tmax, __shfl_xor(tmax, 16, 64));
    tmax = fmaxf(tmax, __shfl_xor(tmax, 32, 64));
    if (lane == 0) wmax[wave] = tmax;
    __syncthreads();
    if (tid == 0) A.tblkmax[blk] = fmaxf(wmax[0], wmax[1]);
}

// ---------- K2: LDS hist + pre-hist + scan + T + packed-key scatter ----------
__global__ __launch_bounds__(1024) void k2_sort(Args A) {
    __shared__ int hist[NBIN];                  // 32 KB
    __shared__ int pre[NBIN];                   // 32 KB
    __shared__ int wtot[16];
    __shared__ float fmax_[16];
    int tid = threadIdx.x, lane = tid & 63, wave = tid >> 6, blk = blockIdx.x;
    #pragma unroll
    for (int e = tid; e < NBIN; e += 1024) { hist[e] = 0; pre[e] = 0; }
    __syncthreads();
    #pragma unroll 4
    for (int e = tid; e < M; e += 1024) {
        float v = (e < N) ? A.t[e] : -A.s[e - N];
        atomicAdd(&hist[t_bin(v)], 1);
    }
    int my0 = blk * 1024;
    #pragma unroll 4
    for (int e = tid; e < my0; e += 1024) {
        float v = (e < N) ? A.t[e] : -A.s[e - N];
        atomicAdd(&pre[t_bin(v)], 1);
    }
    __syncthreads();
    int b0 = tid * 8;
    int c8[8]; int sum = 0;
    #pragma unroll
    for (int g = 0; g < 8; ++g) { c8[g] = sum; sum += hist[b0 + g]; }
    int inc = sum;
    #pragma unroll
    for (int off = 1; off < 64; off <<= 1) {
        int nb = __shfl_up(inc, off, 64);
        if (lane >= off) inc += nb;
    }
    if (lane == 63) wtot[wave] = inc;
    __syncthreads();
    int wbase = 0;
    #pragma unroll
    for (int w = 0; w < 16; ++w) wbase += (w < wave) ? wtot[w] : 0;
    int tstart = wbase + inc - sum;
    #pragma unroll
    for (int g = 0; g < 8; ++g) {
        int bs = tstart + c8[g];
        hist[b0 + g] = bs;
        pre[b0 + g] += bs;
        A.binstart[b0 + g] = bs;                // benign duplicate across blocks
    }
    if (tid == 0 && blk == 0) A.binstart[NBIN] = M;
    float m = (tid < 384) ? A.tblkmax[tid] : -3.4e38f;
    #pragma unroll
    for (int off = 32; off; off >>= 1) m = fmaxf(m, __shfl_xor(m, off, 64));
    if (lane == 0) fmax_[wave] = m;
    __syncthreads();
    if (tid == 0) {
        float mm = fmax_[0];
        #pragma unroll
        for (int w = 1; w < 16; ++w) mm = fmaxf(mm, fmax_[w]);
        A.Thdr[0] = mm;
    }
    __syncthreads();
    {   // exactly one item per thread (slice == blockDim)
        int e = my0 + tid;
        float v = (e < N) ? A.t[e] : -A.s[e - N];
        int pi = (e < N) ? (e + N) : (e - N);   // queries sort before equal keys
        int pos = atomicAdd(&pre[t_bin(v)], 1);
        A.vals64[pos] = ((unsigned long long)f_ord(v) << 32) | (unsigned)pi;
    }
}

// ---------- K3: exact in-bin rank, 4 THREADS per position ----------
__global__ __launch_bounds__(256) void k3_rank(Args A) {
    __shared__ int parts[256];
    int tid = threadIdx.x;
    int li = tid & 63, sub = tid >> 6;
    int p = blockIdx.x * 64 + li;
    unsigned long long kp = A.vals64[p];
    int b = (int)(kp >> (32 + BSHIFT));
    int lo = A.binstart[b], hi = A.binstart[b + 1];
    int len = hi - lo;
    int qlen = (len + 3) >> 2;
    int qlo = lo + sub * qlen;
    if (qlo > hi) qlo = hi;
    int qhi = qlo + qlen;
    if (qhi > hi) qhi = hi;
    int cnt = 0;
    int q = qlo;
    while (q < qhi && (q & 3)) cnt += (int)(A.vals64[q++] < kp);
    int bend = q + ((qhi - q) & ~3);
    #pragma unroll 2
    for (; q < bend; q += 4) {
        ulonglong2 u0 = *(const ulonglong2*)&A.vals64[q];
        ulonglong2 u1 = *(const ulonglong2*)&A.vals64[q + 2];
        cnt += (int)(u0.x < kp) + (int)(u0.y < kp)
             + (int)(u1.x < kp) + (int)(u1.y < kp);
    }
    while (q < qhi) cnt += (int)(A.vals64[q++] < kp);
    parts[sub * 64 + li] = cnt;
    __syncthreads();
    if (sub == 0) {
        int tot = parts[li] + parts[64 + li] + parts[128 + li] + parts[192 + li];
        int pi = (int)(unsigned)(kp & 0xffffffffu);
        A.tfin[lo + tot] = ord_f((unsigned)(kp >> 32));
        A.idfin[lo + tot] = (pi >= N) ? (pi - N) : (pi + N);
    }
}

// ---------- K45: fused sums + barrier + scans + apply, 96 blocks x 256 ------
// ROUND-4 LESSON: at 384 blocks x 64 threads (1.5 waves/CU) every latency
// chain is exposed — k45 ran 116 µs at VALUBusy 3% despite a low-contention
// barrier. The old split k4/k5 were fast BECAUSE they ran 4 waves/CU.
// This version keeps the fusion (x[64] live in registers across the barrier,
// one launch instead of three) but restores the old occupancy: 96 blocks x
// 256 threads, wave w of block b owns chunk b*4+w (old k4 mapping). Barrier
// arrivals drop to 96 on one counter + read-only done flag; 4 waves/CU hide
// the gather/scan latency. 96 blocks <= 256 CUs -> all co-resident, no
// deadlock.
__global__ __launch_bounds__(256) void k45_fused(Args A) {
    int tid = threadIdx.x, wave = tid >> 6, lane = tid & 63;
    int c = blockIdx.x * 4 + wave;              // 384 chunks
    float T = A.Thdr[0];
    float myval = A.tfin[c * 64 + lane];
    int myid = A.idfin[c * 64 + lane];
    float x[64];
    #pragma unroll
    for (int k = 0; k < 64; ++k) {              // 64 independent gathers
        int uid = __shfl(myid, k, 64);
        x[k] = (uid < N) ? A.Wh[(size_t)uid * DOUT + lane] : 0.f;
    }
    float av = 0.f, au = 0.f, svs = 0.f, sus = 0.f;
    #pragma unroll
    for (int k = 0; k < 64; ++k) {
        int uid = __shfl(myid, k, 64);
        if (uid < N) {
            float uval = __shfl(myval, k, 64);
            float wv = expf(0.2f * (uval - T));
            float w2 = wv * wv, w4 = w2 * w2;
            float wu = w4 * wv;                 // exp(uval-T) = wv^5
            av = fmaf(wv, x[k], av); au = fmaf(wu, x[k], au);
            svs += wv; sus += wu;
        }
    }
    // publish aggregates (plain stores), then block-level arrival
    A.VU[c * 64 + lane] = make_float2(av, au);
    if (lane == 0) A.sc[c] = make_float2(svs, sus);
    __threadfence();                            // all 4 waves' stores visible
    __syncthreads();
    if (tid == 0) {
        int old = __hip_atomic_fetch_add(&A.cnt[0], 1,
                                         __ATOMIC_ACQ_REL, __HIP_MEMORY_SCOPE_AGENT);
        if (old == 95)                          // last block -> open the gate
            __hip_atomic_store(&A.cnt[32], 1,
                               __ATOMIC_RELEASE, __HIP_MEMORY_SCOPE_AGENT);
        while (!__hip_atomic_load(&A.cnt[32], __ATOMIC_ACQUIRE, __HIP_MEMORY_SCOPE_AGENT))
            __builtin_amdgcn_s_sleep(2);
    }
    __syncthreads();
    __threadfence();
    // ---- scalar prefix (j<c) and total: lane-split, coalesced -------------
    float psv = 0.f, psu = 0.f, tsu = 0.f;
    #pragma unroll
    for (int b = 0; b < 6; ++b) {
        int j = b * 64 + lane;                  // covers exactly 0..383
        float2 q = A.sc[j];
        tsu += q.y;
        if (j < c) { psv += q.x; psu += q.y; }
    }
    #pragma unroll
    for (int off = 32; off; off >>= 1) {
        psv += __shfl_xor(psv, off, 64);
        psu += __shfl_xor(psu, off, 64);
        tsu += __shfl_xor(tsu, off, 64);
    }
    // ---- column prefix (j<c) and total: 16-wide batched for ILP -----------
    float bv = 0.f, bu = 0.f, tu = 0.f;
    for (int j0 = 0; j0 < NCHUNK; j0 += 16) {
        float2 aa[16];
        #pragma unroll
        for (int k = 0; k < 16; ++k) aa[k] = A.VU[(size_t)(j0 + k) * 64 + lane];
        #pragma unroll
        for (int k = 0; k < 16; ++k) {
            tu += aa[k].y;
            if (j0 + k < c) { bv += aa[k].x; bu += aa[k].y; }
        }
    }
    // ---- apply sweep (old k5 body; x[] reused from phase A) ---------------
    float rv = bv, ru = bu, rvs = psv, rus = psu;
    float tus = tsu;
    #pragma unroll
    for (int k = 0; k < 64; ++k) {
        float uval = __shfl(myval, k, 64);
        int uid = __shfl(myid, k, 64);
        if (uid < N) {                          // key: advance running sums
            float wv = expf(0.2f * (uval - T));
            float w2 = wv * wv, w4 = w2 * w2;
            float wu = w4 * wv;                 // exp(uval-T)
            rv = fmaf(wv, x[k], rv); ru = fmaf(wu, x[k], ru);
            rvs += wv; rus += wu;
        } else {                                // query: emit output row
            int i = uid - N;
            float si = -uval;
            float xx = si + T;
            float mm = fmaxf(xx, 0.2f * xx);
            float cp_ = expf(xx - mm);
            float cn_ = expf(0.2f * xx - mm);
            float num = cn_ * rv + cp_ * (tu - ru);
            float den = cn_ * rvs + cp_ * (tus - rus);
            float r = num / den;
            A.out[(size_t)i * DOUT + lane] = r > 0.f ? r : expm1f(r);
        }
    }
}

extern "C" void kernel_launch(void* const* d_in, const int* in_sizes, int n_in,
                              void* d_out, int out_size, void* d_ws, size_t ws_size,
                              hipStream_t stream) {
    float* ws = (float*)d_ws;
    size_t o = 0;
    Args A;
    A.h = (const float*)d_in[0];
    A.W = (const float*)d_in[1];
    A.a = (const float*)d_in[2];
    A.out = (float*)d_out;
    A.Wh      = ws + o; o += (size_t)N * DOUT;
    A.s       = ws + o; o += N;
    A.t       = ws + o; o += N;
    A.tblkmax = ws + o; o += NCHUNK;            // 384 k1 blocks
    A.Thdr    = ws + o; o += 16;                // keeps o 16B-aligned
    A.vals64  = (unsigned long long*)(ws + o); o += 2 * (size_t)M;
    A.tfin    = ws + o; o += M;
    A.VU      = (float2*)(ws + o); o += 2 * (size_t)NCHUNK * DOUT;
    A.sc      = (float2*)(ws + o); o += 2 * NCHUNK;
    A.idfin    = (int*)(ws + o); o += M;
    A.binstart = (int*)(ws + o); o += NBIN + 16;
    A.cnt      = (int*)(ws + o); o += 64;       // counter + done flag (128B apart)
    // ~4 MB total; barrier cells zeroed by k1 each launch

    k1_gemm <<<N / 32, 128, 0, stream>>>(A);
    k2_sort <<<24, 1024, 0, stream>>>(A);
    k3_rank <<<M / 64, 256, 0, stream>>>(A);
    k45_fused<<<96, 256, 0, stream>>>(A);
}